// Round 8
// baseline (356.214 us; speedup 1.0000x reference)
//
#include <hip/hip_runtime.h>

// Problem constants
#define BGR   256
#define NPG   128
#define EPG   512
#define DIN   128
#define DD    256
#define DD2   512
#define NTOT  (BGR * NPG)   // 32768
#define ETOT  (BGR * EPG)   // 131072
#define NRES  (EPG / 2)
#define MP    136           // padded LDS stride (2-way bank alias = free)
#define S2P   264           // padded stride for s2 (K=256 + 8)

// Output layout (floats)
#define OFF_CEI  0
#define OFF_CW   (2 * BGR * NRES)
#define OFF_FEI  (OFF_CW + BGR * NRES)
#define OFF_FW   (OFF_FEI + 2 * BGR * NRES)
#define OFF_PRED (OFF_FW + BGR * NRES)

typedef unsigned short ushortt;
typedef __attribute__((ext_vector_type(4))) unsigned short us4;
typedef __attribute__((ext_vector_type(8))) unsigned short us8;
typedef __attribute__((ext_vector_type(8))) short short8;
typedef __attribute__((ext_vector_type(4))) float f32x4;

__device__ __forceinline__ ushortt f2bf(float f) {
    unsigned int u = __float_as_uint(f);
    unsigned int r = (u + 0x7fffu + ((u >> 16) & 1u)) >> 16;
    return (ushortt)r;
}
__device__ __forceinline__ float bf2f(ushortt u) {
    return __uint_as_float(((unsigned int)u) << 16);
}

__device__ __forceinline__ void g2lds16(const void* g, void* l) {
    __builtin_amdgcn_global_load_lds(
        (const __attribute__((address_space(1))) unsigned int*)g,
        (__attribute__((address_space(3))) unsigned int*)l, 16, 0, 0);
}

// ---------------------------------------------------------------------------
// Weight transposes only.
__global__ __launch_bounds__(256) void prep_w(const float* __restrict__ W1a,
                                              const float* __restrict__ W1b,
                                              const float* __restrict__ W2a,
                                              const float* __restrict__ W2b,
                                              ushortt* __restrict__ Wt1a,
                                              ushortt* __restrict__ Wt1b,
                                              ushortt* __restrict__ Wt2a,
                                              ushortt* __restrict__ Wt2b) {
    const int idx = blockIdx.x * 256 + threadIdx.x;
    if (idx < 65536) {                       // W1a: 128x512
        const int k = idx >> 9, n = idx & 511;
        Wt1a[n * DIN + k] = f2bf(W1a[idx]);
    } else if (idx < 196608) {               // W1b: 512x256
        const int i = idx - 65536;
        const int k = i >> 8, n = i & 255;
        Wt1b[n * DD2 + k] = f2bf(W1b[i]);
    } else if (idx < 327680) {               // W2a: 256x512
        const int i = idx - 196608;
        const int k = i >> 9, n = i & 511;
        Wt2a[n * DD + k] = f2bf(W2a[i]);
    } else if (idx < 458752) {               // W2b: 512x256
        const int i = idx - 327680;
        const int k = i >> 8, n = i & 255;
        Wt2b[n * DD2 + k] = f2bf(W2b[i]);
    }
}

// ---------------------------------------------------------------------------
// Fused front: per-graph adjacency (LDS) -> s1 = M @ bf16(x) (MFMA, LDS-only)
// -> z1 = s1 @ W1a^T + b1a (MFMA) with fp32 BN partials. One block per graph.
__global__ __launch_bounds__(256) void layer1_front(const float* __restrict__ x,
                                                    const int* __restrict__ ei,
                                                    const ushortt* __restrict__ Wt1a,
                                                    const float* __restrict__ b1a,
                                                    ushortt* __restrict__ z1,
                                                    float* __restrict__ ps,
                                                    float* __restrict__ pq) {
    __shared__ __align__(16) char smem[106496];
    ushortt* Ms = (ushortt*)smem;                 // [128][136]  (later Cs)
    ushortt* XT = (ushortt*)(smem + 34816);       // [128][136]  (later Wc)
    ushortt* S1 = (ushortt*)(smem + 69632);       // [128][136]
    float* redS = (float*)(smem + 104448);        // [2][128]
    float* redQ = (float*)(smem + 105472);        // [2][128]
    int* cnt = (int*)(smem + 34816);              // 64 KB, aliases XT+S1
    const int b = blockIdx.x, t = threadIdx.x;
    const int wave = t >> 6, lane = t & 63;
    const int qd = lane >> 4, r = lane & 15;
    const int wm = (wave >> 1) * 64, wn = (wave & 1) * 64;

    // Phase 0: adjacency counts (order-independent atomics -> deterministic)
    for (int i = t; i < NPG * NPG; i += 256) cnt[i] = 0;
    __syncthreads();
    for (int e = t; e < EPG; e += 256) {
        const int src = ei[b * EPG + e] - b * NPG;
        const int dst = ei[ETOT + b * EPG + e] - b * NPG;
        atomicAdd(&cnt[dst * NPG + src], 1);
    }
    __syncthreads();
#pragma unroll
    for (int k = 0; k < 8; ++k) {
        const int ch = t + k * 256;
        const int m = ch >> 4, sc = (ch & 15) * 8;
#pragma unroll
        for (int e = 0; e < 8; ++e) {
            const int s = sc + e;
            Ms[m * MP + s] = f2bf((float)(cnt[m * NPG + s] + (m == s ? 1 : 0)));
        }
    }
    __syncthreads();   // cnt dead; XT region reusable

    // Phase 1: x -> XT (transpose + bf16), B-operand layout [c][s]
#pragma unroll 4
    for (int it = 0; it < 64; ++it) {
        const int s = it * 2 + (t >> 7);
        const int c = t & 127;
        XT[c * MP + s] = f2bf(x[(size_t)(b * NPG + s) * DIN + c]);
    }
    __syncthreads();

    // Phase 2: s1 = M @ x~  (128x128, K=128)
    {
        f32x4 acc[4][4] = {};
#pragma unroll
        for (int ks = 0; ks < 4; ++ks) {
            const int k0 = ks * 32 + qd * 8;
            short8 af[4], bfr[4];
#pragma unroll
            for (int i = 0; i < 4; ++i)
                af[i] = *(const short8*)&Ms[(wm + i * 16 + r) * MP + k0];
#pragma unroll
            for (int j = 0; j < 4; ++j)
                bfr[j] = *(const short8*)&XT[(wn + j * 16 + r) * MP + k0];
#pragma unroll
            for (int i = 0; i < 4; ++i)
#pragma unroll
                for (int j = 0; j < 4; ++j)
                    acc[i][j] = __builtin_amdgcn_mfma_f32_16x16x32_bf16(af[i], bfr[j], acc[i][j], 0, 0, 0);
        }
        // scatter to S1 [row][k] stride MP
#pragma unroll
        for (int j = 0; j < 4; ++j) {
            const int coll = wn + j * 16 + r;
#pragma unroll
            for (int i = 0; i < 4; ++i)
#pragma unroll
                for (int tt = 0; tt < 4; ++tt)
                    S1[(wm + i * 16 + qd * 4 + tt) * MP + coll] = f2bf(acc[i][j][tt]);
        }
    }

    // Phase 3: z1 = s1 @ W1a^T + b1a, N=512 in 4 chunks of 128
    ushortt* Wc = XT;
    ushortt* Cs = Ms;
    for (int nc = 0; nc < 4; ++nc) {
        __syncthreads();   // prior MFMA reads of Wc / store reads of Cs done
#pragma unroll
        for (int k = 0; k < 8; ++k) {
            const int ch = t + k * 256;
            const int n = ch >> 4, kc = (ch & 15) * 8;
            *(us8*)&Wc[n * MP + kc] = *(const us8*)&Wt1a[(size_t)(nc * 128 + n) * DIN + kc];
        }
        __syncthreads();
        f32x4 acc[4][4] = {};
#pragma unroll
        for (int ks = 0; ks < 4; ++ks) {
            const int k0 = ks * 32 + qd * 8;
            short8 af[4], bfr[4];
#pragma unroll
            for (int i = 0; i < 4; ++i)
                af[i] = *(const short8*)&S1[(wm + i * 16 + r) * MP + k0];
#pragma unroll
            for (int j = 0; j < 4; ++j)
                bfr[j] = *(const short8*)&Wc[(wn + j * 16 + r) * MP + k0];
#pragma unroll
            for (int i = 0; i < 4; ++i)
#pragma unroll
                for (int j = 0; j < 4; ++j)
                    acc[i][j] = __builtin_amdgcn_mfma_f32_16x16x32_bf16(af[i], bfr[j], acc[i][j], 0, 0, 0);
        }
        // epilogue: bias + stats + Cs
#pragma unroll
        for (int j = 0; j < 4; ++j) {
            const int coll = wn + j * 16 + r;
            const float bv = b1a[nc * 128 + coll];
            float s = 0.0f, q = 0.0f;
#pragma unroll
            for (int i = 0; i < 4; ++i)
#pragma unroll
                for (int tt = 0; tt < 4; ++tt) {
                    const float v = acc[i][j][tt] + bv;
                    Cs[(wm + i * 16 + qd * 4 + tt) * 128 + coll] = f2bf(v);
                    s += v;
                    q = fmaf(v, v, q);
                }
            s += __shfl_xor(s, 16); s += __shfl_xor(s, 32);
            q += __shfl_xor(q, 16); q += __shfl_xor(q, 32);
            if (qd == 0) {
                redS[(wave >> 1) * 128 + coll] = s;
                redQ[(wave >> 1) * 128 + coll] = q;
            }
        }
        __syncthreads();
        if (t < 128) {
            ps[(size_t)b * DD2 + nc * 128 + t] = redS[t] + redS[128 + t];
            pq[(size_t)b * DD2 + nc * 128 + t] = redQ[t] + redQ[128 + t];
        }
#pragma unroll
        for (int k = 0; k < 8; ++k) {
            const int ch = t + k * 256;
            const int row = ch >> 4, colc = (ch & 15) * 8;
            *(us8*)&z1[(size_t)(b * NPG + row) * DD2 + nc * 128 + colc] =
                *(const us8*)&Cs[row * 128 + colc];
        }
    }
}

// ---------------------------------------------------------------------------
// h-GEMM with fused BN finalize (fixed-order fp64, replicated per block) and
// BN-apply+ReLU fused into A staging. C = relu(BN(A))@Wt^T + bias, + stats.
#define BM 128
#define BN 128
#define BK 32
__global__ __launch_bounds__(256) void gemm_bn(const ushortt* __restrict__ A,
                                               const ushortt* __restrict__ Wt,
                                               const float* __restrict__ psIn,
                                               const float* __restrict__ pqIn,
                                               const float* __restrict__ g,
                                               const float* __restrict__ be,
                                               const float* __restrict__ bias,
                                               ushortt* __restrict__ C,
                                               float* __restrict__ psOut,
                                               float* __restrict__ pqOut) {
    __shared__ ushortt As[BM * BK];
    __shared__ ushortt Bs[BN * BK];
    __shared__ ushortt Cs[BM * BN];
    __shared__ float redS[2][BN];
    __shared__ float redQ[2][BN];
    __shared__ float scs[DD2], shs[DD2];
    const int tid  = threadIdx.x;
    const int wave = tid >> 6;
    const int lane = tid & 63;
    const int qd = lane >> 4;
    const int r  = lane & 15;
    const int wm = (wave >> 1) * 64;
    const int wn = (wave & 1) * 64;
    const int m0 = blockIdx.y * BM;
    const int n0 = blockIdx.x * BN;
    const int K = DD2, N = DD;

    // Fused finalize: 2 cols per thread, serial fp64 over 256 chunks.
#pragma unroll
    for (int h = 0; h < 2; ++h) {
        const int c = tid + h * 256;
        double s = 0.0, q = 0.0;
#pragma unroll 4
        for (int k = 0; k < 256; ++k) {
            s += (double)psIn[(size_t)k * DD2 + c];
            q += (double)pqIn[(size_t)k * DD2 + c];
        }
        const double mean = s / (double)NTOT;
        const double var = q / (double)NTOT - mean * mean;
        const double rs = 1.0 / sqrt(var + 1e-5);
        const float sc = (float)((double)g[c] * rs);
        scs[c] = sc;
        shs[c] = (float)((double)be[c] - mean * (double)sc);
    }
    __syncthreads();

    f32x4 acc[4][4] = {};

    for (int k0 = 0; k0 < K; k0 += BK) {
#pragma unroll
        for (int s = 0; s < 2; ++s) {
            const int o   = wave * 128 + s * 64 + lane;
            const int row = o >> 2;
            const int cg  = o & 3;
            g2lds16(Wt + (size_t)(n0 + row) * K + k0 + cg * 8,
                    &Bs[(size_t)(wave * 128 + s * 64) * 8]);
        }
#pragma unroll
        for (int s = 0; s < 2; ++s) {
            const int o   = wave * 128 + s * 64 + lane;
            const int row = o >> 2;
            const int cg  = o & 3;
            const us8 a8 = *(const us8*)&A[(size_t)(m0 + row) * K + k0 + cg * 8];
            const float4 s4a = *(const float4*)&scs[k0 + cg * 8];
            const float4 s4b = *(const float4*)&scs[k0 + cg * 8 + 4];
            const float4 h4a = *(const float4*)&shs[k0 + cg * 8];
            const float4 h4b = *(const float4*)&shs[k0 + cg * 8 + 4];
            us8 t8;
            t8[0] = f2bf(fmaxf(fmaf(bf2f(a8[0]), s4a.x, h4a.x), 0.0f));
            t8[1] = f2bf(fmaxf(fmaf(bf2f(a8[1]), s4a.y, h4a.y), 0.0f));
            t8[2] = f2bf(fmaxf(fmaf(bf2f(a8[2]), s4a.z, h4a.z), 0.0f));
            t8[3] = f2bf(fmaxf(fmaf(bf2f(a8[3]), s4a.w, h4a.w), 0.0f));
            t8[4] = f2bf(fmaxf(fmaf(bf2f(a8[4]), s4b.x, h4b.x), 0.0f));
            t8[5] = f2bf(fmaxf(fmaf(bf2f(a8[5]), s4b.y, h4b.y), 0.0f));
            t8[6] = f2bf(fmaxf(fmaf(bf2f(a8[6]), s4b.z, h4b.z), 0.0f));
            t8[7] = f2bf(fmaxf(fmaf(bf2f(a8[7]), s4b.w, h4b.w), 0.0f));
            *(us8*)&As[row * BK + cg * 8] = t8;
        }
        __syncthreads();
        short8 af[4], bfr[4];
#pragma unroll
        for (int i = 0; i < 4; ++i)
            af[i] = *(const short8*)&As[(wm + i * 16 + r) * BK + qd * 8];
#pragma unroll
        for (int j = 0; j < 4; ++j)
            bfr[j] = *(const short8*)&Bs[(wn + j * 16 + r) * BK + qd * 8];
#pragma unroll
        for (int i = 0; i < 4; ++i)
#pragma unroll
            for (int j = 0; j < 4; ++j)
                acc[i][j] = __builtin_amdgcn_mfma_f32_16x16x32_bf16(af[i], bfr[j], acc[i][j], 0, 0, 0);
        __syncthreads();
    }

#pragma unroll
    for (int j = 0; j < 4; ++j) {
        const int coll = wn + j * 16 + r;
        const float bv = bias[n0 + coll];
        float s = 0.0f, q = 0.0f;
#pragma unroll
        for (int i = 0; i < 4; ++i)
#pragma unroll
            for (int t = 0; t < 4; ++t) {
                const float v = acc[i][j][t] + bv;
                Cs[(wm + i * 16 + qd * 4 + t) * BN + coll] = f2bf(v);
                s += v;
                q = fmaf(v, v, q);
            }
        s += __shfl_xor(s, 16); s += __shfl_xor(s, 32);
        q += __shfl_xor(q, 16); q += __shfl_xor(q, 32);
        if (qd == 0) {
            redS[wave >> 1][coll] = s;
            redQ[wave >> 1][coll] = q;
        }
    }
    __syncthreads();
    if (tid < BN) {
        psOut[(size_t)blockIdx.y * N + n0 + tid] = redS[0][tid] + redS[1][tid];
        pqOut[(size_t)blockIdx.y * N + n0 + tid] = redQ[0][tid] + redQ[1][tid];
    }
#pragma unroll
    for (int s8 = 0; s8 < 8; ++s8) {
        const int c    = tid + 256 * s8;
        const int row  = c >> 4;
        const int colc = (c & 15) * 8;
        const us8 v = *(const us8*)&Cs[row * BN + colc];
        *(us8*)&C[(size_t)(m0 + row) * N + n0 + colc] = v;
    }
}

// ---------------------------------------------------------------------------
// Fused middle: finalize(g1) -> adjacency -> post=relu(BN(h1))+vemb staging ->
// s2 = M@post (LDS-only) -> z2 = s2 @ W2a^T + b2a + stats. One block per graph.
__global__ __launch_bounds__(256) void layer2_mid(const ushortt* __restrict__ h1,
                                                  const int* __restrict__ ei,
                                                  const float* __restrict__ psIn,
                                                  const float* __restrict__ pqIn,
                                                  const float* __restrict__ g,
                                                  const float* __restrict__ be,
                                                  const float* __restrict__ vemb,
                                                  const ushortt* __restrict__ Wt2a,
                                                  const float* __restrict__ b2a,
                                                  ushortt* __restrict__ z2,
                                                  float* __restrict__ ps,
                                                  float* __restrict__ pq) {
    __shared__ __align__(16) char smem[141312];
    ushortt* Ms = (ushortt*)smem;                 // [128][136] (later Cs)
    ushortt* PT = (ushortt*)(smem + 34816);       // [128][136] (later Wc)
    ushortt* S2 = (ushortt*)(smem + 69632);       // [128][264] = 67584 B
    float* scs  = (float*)(smem + 137216);        // [256]
    float* shs  = (float*)(smem + 138240);        // [256]
    float* redS = (float*)(smem + 139264);        // [2][128]
    float* redQ = (float*)(smem + 140288);        // [2][128]
    int* cnt = (int*)(smem + 34816);              // 64 KB, aliases PT+S2 head
    const int b = blockIdx.x, t = threadIdx.x;
    const int wave = t >> 6, lane = t & 63;
    const int qd = lane >> 4, r = lane & 15;
    const int wm = (wave >> 1) * 64, wn = (wave & 1) * 64;

    // Phase A: finalize g1/be1 (1 col/thread, fixed serial order)
    {
        const int c = t;
        double s = 0.0, q = 0.0;
#pragma unroll 4
        for (int k = 0; k < 256; ++k) {
            s += (double)psIn[(size_t)k * DD + c];
            q += (double)pqIn[(size_t)k * DD + c];
        }
        const double mean = s / (double)NTOT;
        const double var = q / (double)NTOT - mean * mean;
        const double rs = 1.0 / sqrt(var + 1e-5);
        const float sc = (float)((double)g[c] * rs);
        scs[c] = sc;
        shs[c] = (float)((double)be[c] - mean * (double)sc);
    }
    // Phase B: adjacency
    for (int i = t; i < NPG * NPG; i += 256) cnt[i] = 0;
    __syncthreads();
    for (int e = t; e < EPG; e += 256) {
        const int src = ei[b * EPG + e] - b * NPG;
        const int dst = ei[ETOT + b * EPG + e] - b * NPG;
        atomicAdd(&cnt[dst * NPG + src], 1);
    }
    __syncthreads();
#pragma unroll
    for (int k = 0; k < 8; ++k) {
        const int ch = t + k * 256;
        const int m = ch >> 4, sc = (ch & 15) * 8;
#pragma unroll
        for (int e = 0; e < 8; ++e) {
            const int s = sc + e;
            Ms[m * MP + s] = f2bf((float)(cnt[m * NPG + s] + (m == s ? 1 : 0)));
        }
    }
    __syncthreads();   // cnt dead

    // Phase C: two column-halves: stage post^T, MFMA into S2
    for (int nb = 0; nb < 2; ++nb) {
        const int cl = t & 127;
        const int c = nb * 128 + cl;
        const float scv = scs[c], shv = shs[c], vev = vemb[c];
#pragma unroll 4
        for (int it = 0; it < 64; ++it) {
            const int s = it * 2 + (t >> 7);
            float v = fmaf(bf2f(h1[(size_t)(b * NPG + s) * DD + c]), scv, shv);
            PT[cl * MP + s] = f2bf(fmaxf(v, 0.0f) + vev);
        }
        __syncthreads();
        f32x4 acc[4][4] = {};
#pragma unroll
        for (int ks = 0; ks < 4; ++ks) {
            const int k0 = ks * 32 + qd * 8;
            short8 af[4], bfr[4];
#pragma unroll
            for (int i = 0; i < 4; ++i)
                af[i] = *(const short8*)&Ms[(wm + i * 16 + r) * MP + k0];
#pragma unroll
            for (int j = 0; j < 4; ++j)
                bfr[j] = *(const short8*)&PT[(wn + j * 16 + r) * MP + k0];
#pragma unroll
            for (int i = 0; i < 4; ++i)
#pragma unroll
                for (int j = 0; j < 4; ++j)
                    acc[i][j] = __builtin_amdgcn_mfma_f32_16x16x32_bf16(af[i], bfr[j], acc[i][j], 0, 0, 0);
        }
#pragma unroll
        for (int j = 0; j < 4; ++j) {
            const int coll = wn + j * 16 + r;
#pragma unroll
            for (int i = 0; i < 4; ++i)
#pragma unroll
                for (int tt = 0; tt < 4; ++tt)
                    S2[(wm + i * 16 + qd * 4 + tt) * S2P + nb * 128 + coll] = f2bf(acc[i][j][tt]);
        }
        __syncthreads();   // PT reads done before restage / Wc reuse
    }

    // Phase D: z2 = s2 @ W2a^T + b2a (K=256 via 2 halves), N=512 in 4 chunks
    ushortt* Wc = PT;
    ushortt* Cs = Ms;
    for (int nc = 0; nc < 4; ++nc) {
        f32x4 acc[4][4] = {};
#pragma unroll
        for (int kh = 0; kh < 2; ++kh) {
            __syncthreads();   // prior Wc reads / Cs-store reads done
#pragma unroll
            for (int k = 0; k < 8; ++k) {
                const int ch = t + k * 256;
                const int n = ch >> 4, kc = (ch & 15) * 8;
                *(us8*)&Wc[n * MP + kc] =
                    *(const us8*)&Wt2a[(size_t)(nc * 128 + n) * DD + kh * 128 + kc];
            }
            __syncthreads();
#pragma unroll
            for (int ks = 0; ks < 4; ++ks) {
                const int k0 = ks * 32 + qd * 8;
                short8 af[4], bfr[4];
#pragma unroll
                for (int i = 0; i < 4; ++i)
                    af[i] = *(const short8*)&S2[(wm + i * 16 + r) * S2P + kh * 128 + k0];
#pragma unroll
                for (int j = 0; j < 4; ++j)
                    bfr[j] = *(const short8*)&Wc[(wn + j * 16 + r) * MP + k0];
#pragma unroll
                for (int i = 0; i < 4; ++i)
#pragma unroll
                    for (int j = 0; j < 4; ++j)
                        acc[i][j] = __builtin_amdgcn_mfma_f32_16x16x32_bf16(af[i], bfr[j], acc[i][j], 0, 0, 0);
            }
        }
        // epilogue
#pragma unroll
        for (int j = 0; j < 4; ++j) {
            const int coll = wn + j * 16 + r;
            const float bv = b2a[nc * 128 + coll];
            float s = 0.0f, q = 0.0f;
#pragma unroll
            for (int i = 0; i < 4; ++i)
#pragma unroll
                for (int tt = 0; tt < 4; ++tt) {
                    const float v = acc[i][j][tt] + bv;
                    Cs[(wm + i * 16 + qd * 4 + tt) * 128 + coll] = f2bf(v);
                    s += v;
                    q = fmaf(v, v, q);
                }
            s += __shfl_xor(s, 16); s += __shfl_xor(s, 32);
            q += __shfl_xor(q, 16); q += __shfl_xor(q, 32);
            if (qd == 0) {
                redS[(wave >> 1) * 128 + coll] = s;
                redQ[(wave >> 1) * 128 + coll] = q;
            }
        }
        __syncthreads();
        if (t < 128) {
            ps[(size_t)b * DD2 + nc * 128 + t] = redS[t] + redS[128 + t];
            pq[(size_t)b * DD2 + nc * 128 + t] = redQ[t] + redQ[128 + t];
        }
#pragma unroll
        for (int k = 0; k < 8; ++k) {
            const int ch = t + k * 256;
            const int row = ch >> 4, colc = (ch & 15) * 8;
            *(us8*)&z2[(size_t)(b * NPG + row) * DD2 + nc * 128 + colc] =
                *(const us8*)&Cs[row * 128 + colc];
        }
    }
}

// ---------------------------------------------------------------------------
// Mega tail: per-graph block (512 thr). finalize(g2,be2) -> node dots ->
// edge scores -> stable descending rank-sort -> output writes.
__global__ __launch_bounds__(EPG) void sort_mega(const ushortt* __restrict__ h2,
                                                 const float* __restrict__ psum,
                                                 const float* __restrict__ psumsq,
                                                 const float* __restrict__ g,
                                                 const float* __restrict__ be,
                                                 const float* __restrict__ Wl,
                                                 const float* __restrict__ bl,
                                                 const int* __restrict__ ei,
                                                 float* __restrict__ out) {
    __shared__ double redS[2][DD];
    __shared__ double redQ[2][DD];
    __shared__ float scs[DD], shs[DD];
    __shared__ float pa[NPG], pb[NPG];
    __shared__ float pw[EPG];
    __shared__ int ord[EPG];
    const int b = blockIdx.x, t = threadIdx.x;
    {
        const int c = t & 255, half = t >> 8;
        double s = 0.0, q = 0.0;
#pragma unroll 4
        for (int k = half * 128; k < half * 128 + 128; ++k) {
            s += (double)psum[(size_t)k * DD + c];
            q += (double)psumsq[(size_t)k * DD + c];
        }
        redS[half][c] = s;
        redQ[half][c] = q;
    }
    __syncthreads();
    if (t < DD) {
        const double s = redS[0][t] + redS[1][t];
        const double q = redQ[0][t] + redQ[1][t];
        const double mean = s / (double)NTOT;
        const double var = q / (double)NTOT - mean * mean;
        const double rs = 1.0 / sqrt(var + 1e-5);
        const float sc = (float)((double)g[t] * rs);
        scs[t] = sc;
        shs[t] = (float)((double)be[t] - mean * (double)sc);
    }
    __syncthreads();
    {
        const int wave = t >> 6, lane = t & 63;
        const float4 w0 = *(const float4*)&Wl[lane * 4];
        const float4 w1 = *(const float4*)&Wl[DD + lane * 4];
        const float4 sc4 = *(const float4*)&scs[lane * 4];
        const float4 sh4 = *(const float4*)&shs[lane * 4];
        for (int n = wave; n < NPG; n += 8) {
            const us4 z4 = *(const us4*)&h2[(size_t)(b * NPG + n) * DD + lane * 4];
            const float x0 = fmaf(bf2f(z4.x), sc4.x, sh4.x);
            const float x1 = fmaf(bf2f(z4.y), sc4.y, sh4.y);
            const float x2 = fmaf(bf2f(z4.z), sc4.z, sh4.z);
            const float x3 = fmaf(bf2f(z4.w), sc4.w, sh4.w);
            float sa = x0 * w0.x + x1 * w0.y + x2 * w0.z + x3 * w0.w;
            float sb = x0 * w1.x + x1 * w1.y + x2 * w1.z + x3 * w1.w;
#pragma unroll
            for (int off = 32; off >= 1; off >>= 1) {
                sa += __shfl_down(sa, off);
                sb += __shfl_down(sb, off);
            }
            if (lane == 0) { pa[n] = sa; pb[n] = sb; }
        }
    }
    __syncthreads();
    const int rl = ei[b * EPG + t] - b * NPG;
    const int cl = ei[ETOT + b * EPG + t] - b * NPG;
    const float v = pa[rl] + pb[cl] + bl[0];
    pw[t] = v;
    out[OFF_PRED + b * EPG + t] = v;
    __syncthreads();
    int rank = 0;
#pragma unroll 8
    for (int k = 0; k < EPG; ++k) {
        const float u = pw[k];
        rank += (u > v) || (u == v && k < t);
    }
    ord[rank] = t;
    __syncthreads();
    const int j = ord[t];
    const float wv = pw[j];
    const float e0 = (float)ei[b * EPG + j];
    const float e1 = (float)ei[ETOT + b * EPG + j];
    if (t < NRES) {
        out[OFF_CEI + b * NRES + t] = e0;
        out[OFF_CEI + BGR * NRES + b * NRES + t] = e1;
        out[OFF_CW + b * NRES + t] = wv;
    } else {
        const int p = t - NRES;
        out[OFF_FEI + b * NRES + p] = e0;
        out[OFF_FEI + BGR * NRES + b * NRES + p] = e1;
        out[OFF_FW + b * NRES + p] = -wv;
    }
}

// ---------------------------------------------------------------------------
extern "C" void kernel_launch(void* const* d_in, const int* in_sizes, int n_in,
                              void* d_out, int out_size, void* d_ws, size_t ws_size,
                              hipStream_t stream) {
    (void)in_sizes; (void)n_in; (void)out_size; (void)ws_size;
    const float* x    = (const float*)d_in[0];
    const int*   ei   = (const int*)d_in[1];
    const float* vemb = (const float*)d_in[3];
    const float* W1a  = (const float*)d_in[4];
    const float* b1a  = (const float*)d_in[5];
    const float* g1a  = (const float*)d_in[6];
    const float* be1a = (const float*)d_in[7];
    const float* W1b  = (const float*)d_in[8];
    const float* b1b  = (const float*)d_in[9];
    const float* g1   = (const float*)d_in[10];
    const float* be1  = (const float*)d_in[11];
    const float* W2a  = (const float*)d_in[12];
    const float* b2a  = (const float*)d_in[13];
    const float* g2a  = (const float*)d_in[14];
    const float* be2a = (const float*)d_in[15];
    const float* W2b  = (const float*)d_in[16];
    const float* b2b  = (const float*)d_in[17];
    const float* g2   = (const float*)d_in[18];
    const float* be2  = (const float*)d_in[19];
    const float* Wl   = (const float*)d_in[20];
    const float* bl   = (const float*)d_in[21];
    float* out = (float*)d_out;

    char* wp = (char*)d_ws;
    auto alloc = [&](size_t bytes) -> char* {
        char* r = wp;
        wp += (bytes + 255) & ~(size_t)255;
        return r;
    };
    ushortt* zb    = (ushortt*)alloc((size_t)NTOT * 512 * 2);  // z1 / z2
    ushortt* bufC  = (ushortt*)alloc((size_t)NTOT * 256 * 2);  // h1 / h2
    ushortt* Wt1a  = (ushortt*)alloc((size_t)DIN * DD2 * 2);
    ushortt* Wt1b  = (ushortt*)alloc((size_t)DD2 * DD * 2);
    ushortt* Wt2a  = (ushortt*)alloc((size_t)DD * DD2 * 2);
    ushortt* Wt2b  = (ushortt*)alloc((size_t)DD2 * DD * 2);
    float*   psA   = (float*)alloc((size_t)256 * DD2 * 4);     // z-stats
    float*   pqA   = (float*)alloc((size_t)256 * DD2 * 4);
    float*   psB   = (float*)alloc((size_t)256 * DD * 4);      // h-stats
    float*   pqB   = (float*)alloc((size_t)256 * DD * 4);

    // 1) weights
    prep_w<<<1792, 256, 0, stream>>>(W1a, W1b, W2a, W2b, Wt1a, Wt1b, Wt2a, Wt2b);

    // 2) adj + agg1 + z1 GEMM (+stats)
    layer1_front<<<BGR, 256, 0, stream>>>(x, ei, Wt1a, b1a, zb, psA, pqA);

    // 3) h1 = relu(BN(z1)) @ W1b + b1b  (finalize+apply fused, +stats)
    gemm_bn<<<dim3(DD / BN, NTOT / BM), 256, 0, stream>>>(zb, Wt1b, psA, pqA, g1a, be1a, b1b, bufC, psB, pqB);

    // 4) finalize(g1) + post + adj + agg2 + z2 GEMM (+stats)
    layer2_mid<<<BGR, 256, 0, stream>>>(bufC, ei, psB, pqB, g1, be1, vemb, Wt2a, b2a, zb, psA, pqA);

    // 5) h2 = relu(BN(z2)) @ W2b + b2b  (fused, +stats)
    gemm_bn<<<dim3(DD / BN, NTOT / BM), 256, 0, stream>>>(zb, Wt2b, psA, pqA, g2a, be2a, b2b, bufC, psB, pqB);

    // 6) mega tail
    sort_mega<<<BGR, EPG, 0, stream>>>(bufC, psB, pqB, g2, be2, Wl, bl, ei, out);
}

// Round 9
// 330.723 us; speedup vs baseline: 1.0771x; 1.0771x over previous
//
#include <hip/hip_runtime.h>

// Problem constants
#define BGR   256
#define NPG   128
#define EPG   512
#define DIN   128
#define DD    256
#define DD2   512
#define NTOT  (BGR * NPG)   // 32768
#define ETOT  (BGR * EPG)   // 131072
#define NRES  (EPG / 2)
#define NCHUNK 256
#define MP    136           // padded LDS stride
#define S2P   264           // padded stride for s2

// Output layout (floats)
#define OFF_CEI  0
#define OFF_CW   (2 * BGR * NRES)
#define OFF_FEI  (OFF_CW + BGR * NRES)
#define OFF_FW   (OFF_FEI + 2 * BGR * NRES)
#define OFF_PRED (OFF_FW + BGR * NRES)

typedef unsigned short ushortt;
typedef __attribute__((ext_vector_type(4))) unsigned short us4;
typedef __attribute__((ext_vector_type(8))) unsigned short us8;
typedef __attribute__((ext_vector_type(8))) short short8;
typedef __attribute__((ext_vector_type(4))) float f32x4;

__device__ __forceinline__ ushortt f2bf(float f) {
    unsigned int u = __float_as_uint(f);
    unsigned int r = (u + 0x7fffu + ((u >> 16) & 1u)) >> 16;
    return (ushortt)r;
}
__device__ __forceinline__ float bf2f(ushortt u) {
    return __uint_as_float(((unsigned int)u) << 16);
}

__device__ __forceinline__ void g2lds16(const void* g, void* l) {
    __builtin_amdgcn_global_load_lds(
        (const __attribute__((address_space(1))) unsigned int*)g,
        (__attribute__((address_space(3))) unsigned int*)l, 16, 0, 0);
}

// ---------------------------------------------------------------------------
__global__ __launch_bounds__(256) void prep_w(const float* __restrict__ W1a,
                                              const float* __restrict__ W1b,
                                              const float* __restrict__ W2a,
                                              const float* __restrict__ W2b,
                                              ushortt* __restrict__ Wt1a,
                                              ushortt* __restrict__ Wt1b,
                                              ushortt* __restrict__ Wt2a,
                                              ushortt* __restrict__ Wt2b) {
    const int idx = blockIdx.x * 256 + threadIdx.x;
    if (idx < 65536) {                       // W1a: 128x512
        const int k = idx >> 9, n = idx & 511;
        Wt1a[n * DIN + k] = f2bf(W1a[idx]);
    } else if (idx < 196608) {               // W1b: 512x256
        const int i = idx - 65536;
        const int k = i >> 8, n = i & 255;
        Wt1b[n * DD2 + k] = f2bf(W1b[i]);
    } else if (idx < 327680) {               // W2a: 256x512
        const int i = idx - 196608;
        const int k = i >> 9, n = i & 511;
        Wt2a[n * DD + k] = f2bf(W2a[i]);
    } else if (idx < 458752) {               // W2b: 512x256
        const int i = idx - 327680;
        const int k = i >> 8, n = i & 255;
        Wt2b[n * DD2 + k] = f2bf(W2b[i]);
    }
}

// ---------------------------------------------------------------------------
// BN finalize: one thread per column, fixed serial fp64 order (deterministic).
__global__ __launch_bounds__(256) void bn_finalize(const float* __restrict__ psum,
                                                   const float* __restrict__ psumsq,
                                                   const float* __restrict__ g,
                                                   const float* __restrict__ be,
                                                   int ncols,
                                                   float* __restrict__ scale,
                                                   float* __restrict__ shift) {
    const int c = blockIdx.x * 256 + threadIdx.x;
    double s = 0.0, s2 = 0.0;
    for (int k = 0; k < NCHUNK; ++k) {
        s += (double)psum[(size_t)k * ncols + c];
        s2 += (double)psumsq[(size_t)k * ncols + c];
    }
    const double mean = s / (double)NTOT;
    const double var = s2 / (double)NTOT - mean * mean;
    const double rs = 1.0 / sqrt(var + 1e-5);
    const float sc = (float)((double)g[c] * rs);
    scale[c] = sc;
    shift[c] = (float)((double)be[c] - mean * (double)sc);
}

// ---------------------------------------------------------------------------
// Fused front: per-graph adjacency (LDS) -> s1 = M @ bf16(x) (MFMA, LDS-only)
// -> z1 = s1 @ W1a^T + b1a (MFMA) with fp32 BN partials. One block per graph.
__global__ __launch_bounds__(256) void layer1_front(const float* __restrict__ x,
                                                    const int* __restrict__ ei,
                                                    const ushortt* __restrict__ Wt1a,
                                                    const float* __restrict__ b1a,
                                                    ushortt* __restrict__ z1,
                                                    float* __restrict__ ps,
                                                    float* __restrict__ pq) {
    __shared__ __align__(16) char smem[106496];
    ushortt* Ms = (ushortt*)smem;                 // [128][136]  (later Cs)
    ushortt* XT = (ushortt*)(smem + 34816);       // [128][136]  (later Wc)
    ushortt* S1 = (ushortt*)(smem + 69632);       // [128][136]
    float* redS = (float*)(smem + 104448);        // [2][128]
    float* redQ = (float*)(smem + 105472);        // [2][128]
    int* cnt = (int*)(smem + 34816);              // 64 KB, aliases XT+S1
    const int b = blockIdx.x, t = threadIdx.x;
    const int wave = t >> 6, lane = t & 63;
    const int qd = lane >> 4, r = lane & 15;
    const int wm = (wave >> 1) * 64, wn = (wave & 1) * 64;

    // Phase 0: adjacency counts (order-independent atomics -> deterministic)
    for (int i = t; i < NPG * NPG; i += 256) cnt[i] = 0;
    __syncthreads();
    for (int e = t; e < EPG; e += 256) {
        const int src = ei[b * EPG + e] - b * NPG;
        const int dst = ei[ETOT + b * EPG + e] - b * NPG;
        atomicAdd(&cnt[dst * NPG + src], 1);
    }
    __syncthreads();
#pragma unroll
    for (int k = 0; k < 8; ++k) {
        const int ch = t + k * 256;
        const int m = ch >> 4, sc = (ch & 15) * 8;
#pragma unroll
        for (int e = 0; e < 8; ++e) {
            const int s = sc + e;
            Ms[m * MP + s] = f2bf((float)(cnt[m * NPG + s] + (m == s ? 1 : 0)));
        }
    }
    __syncthreads();   // cnt dead; XT region reusable

    // Phase 1: x -> XT (transpose + bf16), B-operand layout [c][s]
#pragma unroll 4
    for (int it = 0; it < 64; ++it) {
        const int s = it * 2 + (t >> 7);
        const int c = t & 127;
        XT[c * MP + s] = f2bf(x[(size_t)(b * NPG + s) * DIN + c]);
    }
    __syncthreads();

    // Phase 2: s1 = M @ x~  (128x128, K=128)
    {
        f32x4 acc[4][4] = {};
#pragma unroll
        for (int ks = 0; ks < 4; ++ks) {
            const int k0 = ks * 32 + qd * 8;
            short8 af[4], bfr[4];
#pragma unroll
            for (int i = 0; i < 4; ++i)
                af[i] = *(const short8*)&Ms[(wm + i * 16 + r) * MP + k0];
#pragma unroll
            for (int j = 0; j < 4; ++j)
                bfr[j] = *(const short8*)&XT[(wn + j * 16 + r) * MP + k0];
#pragma unroll
            for (int i = 0; i < 4; ++i)
#pragma unroll
                for (int j = 0; j < 4; ++j)
                    acc[i][j] = __builtin_amdgcn_mfma_f32_16x16x32_bf16(af[i], bfr[j], acc[i][j], 0, 0, 0);
        }
#pragma unroll
        for (int j = 0; j < 4; ++j) {
            const int coll = wn + j * 16 + r;
#pragma unroll
            for (int i = 0; i < 4; ++i)
#pragma unroll
                for (int tt = 0; tt < 4; ++tt)
                    S1[(wm + i * 16 + qd * 4 + tt) * MP + coll] = f2bf(acc[i][j][tt]);
        }
    }

    // Phase 3: z1 = s1 @ W1a^T + b1a, N=512 in 4 chunks of 128
    ushortt* Wc = XT;
    ushortt* Cs = Ms;
    for (int nc = 0; nc < 4; ++nc) {
        __syncthreads();
#pragma unroll
        for (int k = 0; k < 8; ++k) {
            const int ch = t + k * 256;
            const int n = ch >> 4, kc = (ch & 15) * 8;
            *(us8*)&Wc[n * MP + kc] = *(const us8*)&Wt1a[(size_t)(nc * 128 + n) * DIN + kc];
        }
        __syncthreads();
        f32x4 acc[4][4] = {};
#pragma unroll
        for (int ks = 0; ks < 4; ++ks) {
            const int k0 = ks * 32 + qd * 8;
            short8 af[4], bfr[4];
#pragma unroll
            for (int i = 0; i < 4; ++i)
                af[i] = *(const short8*)&S1[(wm + i * 16 + r) * MP + k0];
#pragma unroll
            for (int j = 0; j < 4; ++j)
                bfr[j] = *(const short8*)&Wc[(wn + j * 16 + r) * MP + k0];
#pragma unroll
            for (int i = 0; i < 4; ++i)
#pragma unroll
                for (int j = 0; j < 4; ++j)
                    acc[i][j] = __builtin_amdgcn_mfma_f32_16x16x32_bf16(af[i], bfr[j], acc[i][j], 0, 0, 0);
        }
#pragma unroll
        for (int j = 0; j < 4; ++j) {
            const int coll = wn + j * 16 + r;
            const float bv = b1a[nc * 128 + coll];
            float s = 0.0f, q = 0.0f;
#pragma unroll
            for (int i = 0; i < 4; ++i)
#pragma unroll
                for (int tt = 0; tt < 4; ++tt) {
                    const float v = acc[i][j][tt] + bv;
                    Cs[(wm + i * 16 + qd * 4 + tt) * 128 + coll] = f2bf(v);
                    s += v;
                    q = fmaf(v, v, q);
                }
            s += __shfl_xor(s, 16); s += __shfl_xor(s, 32);
            q += __shfl_xor(q, 16); q += __shfl_xor(q, 32);
            if (qd == 0) {
                redS[(wave >> 1) * 128 + coll] = s;
                redQ[(wave >> 1) * 128 + coll] = q;
            }
        }
        __syncthreads();
        if (t < 128) {
            ps[(size_t)b * DD2 + nc * 128 + t] = redS[t] + redS[128 + t];
            pq[(size_t)b * DD2 + nc * 128 + t] = redQ[t] + redQ[128 + t];
        }
#pragma unroll
        for (int k = 0; k < 8; ++k) {
            const int ch = t + k * 256;
            const int row = ch >> 4, colc = (ch & 15) * 8;
            *(us8*)&z1[(size_t)(b * NPG + row) * DD2 + nc * 128 + colc] =
                *(const us8*)&Cs[row * 128 + colc];
        }
    }
}

// ---------------------------------------------------------------------------
// h-GEMM: C = relu(BN(A))@Wt^T + bias, scale/shift precomputed, + fp32 stats.
#define BM 128
#define BN 128
#define BK 32
__global__ __launch_bounds__(256) void gemm_bn(const ushortt* __restrict__ A,
                                               const ushortt* __restrict__ Wt,
                                               const float* __restrict__ scale,
                                               const float* __restrict__ shift,
                                               const float* __restrict__ bias,
                                               ushortt* __restrict__ C,
                                               float* __restrict__ psOut,
                                               float* __restrict__ pqOut) {
    __shared__ ushortt As[BM * BK];
    __shared__ ushortt Bs[BN * BK];
    __shared__ ushortt Cs[BM * BN];
    __shared__ float redS[2][BN];
    __shared__ float redQ[2][BN];
    __shared__ float scs[DD2], shs[DD2];
    const int tid  = threadIdx.x;
    const int wave = tid >> 6;
    const int lane = tid & 63;
    const int qd = lane >> 4;
    const int r  = lane & 15;
    const int wm = (wave >> 1) * 64;
    const int wn = (wave & 1) * 64;
    const int m0 = blockIdx.y * BM;
    const int n0 = blockIdx.x * BN;
    const int K = DD2, N = DD;

    for (int i = tid; i < K; i += 256) {
        scs[i] = scale[i];
        shs[i] = shift[i];
    }
    __syncthreads();

    f32x4 acc[4][4] = {};

    for (int k0 = 0; k0 < K; k0 += BK) {
#pragma unroll
        for (int s = 0; s < 2; ++s) {
            const int o   = wave * 128 + s * 64 + lane;
            const int row = o >> 2;
            const int cg  = o & 3;
            g2lds16(Wt + (size_t)(n0 + row) * K + k0 + cg * 8,
                    &Bs[(size_t)(wave * 128 + s * 64) * 8]);
        }
#pragma unroll
        for (int s = 0; s < 2; ++s) {
            const int o   = wave * 128 + s * 64 + lane;
            const int row = o >> 2;
            const int cg  = o & 3;
            const us8 a8 = *(const us8*)&A[(size_t)(m0 + row) * K + k0 + cg * 8];
            const float4 s4a = *(const float4*)&scs[k0 + cg * 8];
            const float4 s4b = *(const float4*)&scs[k0 + cg * 8 + 4];
            const float4 h4a = *(const float4*)&shs[k0 + cg * 8];
            const float4 h4b = *(const float4*)&shs[k0 + cg * 8 + 4];
            us8 t8;
            t8[0] = f2bf(fmaxf(fmaf(bf2f(a8[0]), s4a.x, h4a.x), 0.0f));
            t8[1] = f2bf(fmaxf(fmaf(bf2f(a8[1]), s4a.y, h4a.y), 0.0f));
            t8[2] = f2bf(fmaxf(fmaf(bf2f(a8[2]), s4a.z, h4a.z), 0.0f));
            t8[3] = f2bf(fmaxf(fmaf(bf2f(a8[3]), s4a.w, h4a.w), 0.0f));
            t8[4] = f2bf(fmaxf(fmaf(bf2f(a8[4]), s4b.x, h4b.x), 0.0f));
            t8[5] = f2bf(fmaxf(fmaf(bf2f(a8[5]), s4b.y, h4b.y), 0.0f));
            t8[6] = f2bf(fmaxf(fmaf(bf2f(a8[6]), s4b.z, h4b.z), 0.0f));
            t8[7] = f2bf(fmaxf(fmaf(bf2f(a8[7]), s4b.w, h4b.w), 0.0f));
            *(us8*)&As[row * BK + cg * 8] = t8;
        }
        __syncthreads();
        short8 af[4], bfr[4];
#pragma unroll
        for (int i = 0; i < 4; ++i)
            af[i] = *(const short8*)&As[(wm + i * 16 + r) * BK + qd * 8];
#pragma unroll
        for (int j = 0; j < 4; ++j)
            bfr[j] = *(const short8*)&Bs[(wn + j * 16 + r) * BK + qd * 8];
#pragma unroll
        for (int i = 0; i < 4; ++i)
#pragma unroll
            for (int j = 0; j < 4; ++j)
                acc[i][j] = __builtin_amdgcn_mfma_f32_16x16x32_bf16(af[i], bfr[j], acc[i][j], 0, 0, 0);
        __syncthreads();
    }

#pragma unroll
    for (int j = 0; j < 4; ++j) {
        const int coll = wn + j * 16 + r;
        const float bv = bias[n0 + coll];
        float s = 0.0f, q = 0.0f;
#pragma unroll
        for (int i = 0; i < 4; ++i)
#pragma unroll
            for (int t = 0; t < 4; ++t) {
                const float v = acc[i][j][t] + bv;
                Cs[(wm + i * 16 + qd * 4 + t) * BN + coll] = f2bf(v);
                s += v;
                q = fmaf(v, v, q);
            }
        s += __shfl_xor(s, 16); s += __shfl_xor(s, 32);
        q += __shfl_xor(q, 16); q += __shfl_xor(q, 32);
        if (qd == 0) {
            redS[wave >> 1][coll] = s;
            redQ[wave >> 1][coll] = q;
        }
    }
    __syncthreads();
    if (tid < BN) {
        psOut[(size_t)blockIdx.y * N + n0 + tid] = redS[0][tid] + redS[1][tid];
        pqOut[(size_t)blockIdx.y * N + n0 + tid] = redQ[0][tid] + redQ[1][tid];
    }
#pragma unroll
    for (int s8 = 0; s8 < 8; ++s8) {
        const int c    = tid + 256 * s8;
        const int row  = c >> 4;
        const int colc = (c & 15) * 8;
        const us8 v = *(const us8*)&Cs[row * BN + colc];
        *(us8*)&C[(size_t)(m0 + row) * N + n0 + colc] = v;
    }
}

// ---------------------------------------------------------------------------
// Fused middle: adjacency -> post=relu(BN(h1))+vemb staging (scale/shift
// precomputed) -> s2 = M@post (LDS-only) -> z2 = s2 @ W2a^T + b2a + stats.
__global__ __launch_bounds__(256) void layer2_mid(const ushortt* __restrict__ h1,
                                                  const int* __restrict__ ei,
                                                  const float* __restrict__ scale,
                                                  const float* __restrict__ shift,
                                                  const float* __restrict__ vemb,
                                                  const ushortt* __restrict__ Wt2a,
                                                  const float* __restrict__ b2a,
                                                  ushortt* __restrict__ z2,
                                                  float* __restrict__ ps,
                                                  float* __restrict__ pq) {
    __shared__ __align__(16) char smem[141312];
    ushortt* Ms = (ushortt*)smem;                 // [128][136] (later Cs)
    ushortt* PT = (ushortt*)(smem + 34816);       // [128][136] (later Wc)
    ushortt* S2 = (ushortt*)(smem + 69632);       // [128][264]
    float* scs  = (float*)(smem + 137216);        // [256]
    float* shs  = (float*)(smem + 138240);        // [256]
    float* redS = (float*)(smem + 139264);        // [2][128]
    float* redQ = (float*)(smem + 140288);        // [2][128]
    int* cnt = (int*)(smem + 34816);              // 64 KB, aliases PT+S2 head
    const int b = blockIdx.x, t = threadIdx.x;
    const int wave = t >> 6, lane = t & 63;
    const int qd = lane >> 4, r = lane & 15;
    const int wm = (wave >> 1) * 64, wn = (wave & 1) * 64;

    // Phase B: adjacency (cnt aliases PT/S2 head; scs/shs region is separate)
    for (int i = t; i < NPG * NPG; i += 256) cnt[i] = 0;
    __syncthreads();
    for (int e = t; e < EPG; e += 256) {
        const int src = ei[b * EPG + e] - b * NPG;
        const int dst = ei[ETOT + b * EPG + e] - b * NPG;
        atomicAdd(&cnt[dst * NPG + src], 1);
    }
    if (t < 256) { scs[t] = scale[t]; shs[t] = shift[t]; }
    __syncthreads();
#pragma unroll
    for (int k = 0; k < 8; ++k) {
        const int ch = t + k * 256;
        const int m = ch >> 4, sc = (ch & 15) * 8;
#pragma unroll
        for (int e = 0; e < 8; ++e) {
            const int s = sc + e;
            Ms[m * MP + s] = f2bf((float)(cnt[m * NPG + s] + (m == s ? 1 : 0)));
        }
    }
    __syncthreads();   // cnt dead

    // Phase C: two column-halves: stage post^T, MFMA into S2
    for (int nb = 0; nb < 2; ++nb) {
        const int cl = t & 127;
        const int c = nb * 128 + cl;
        const float scv = scs[c], shv = shs[c], vev = vemb[c];
#pragma unroll 4
        for (int it = 0; it < 64; ++it) {
            const int s = it * 2 + (t >> 7);
            float v = fmaf(bf2f(h1[(size_t)(b * NPG + s) * DD + c]), scv, shv);
            PT[cl * MP + s] = f2bf(fmaxf(v, 0.0f) + vev);
        }
        __syncthreads();
        f32x4 acc[4][4] = {};
#pragma unroll
        for (int ks = 0; ks < 4; ++ks) {
            const int k0 = ks * 32 + qd * 8;
            short8 af[4], bfr[4];
#pragma unroll
            for (int i = 0; i < 4; ++i)
                af[i] = *(const short8*)&Ms[(wm + i * 16 + r) * MP + k0];
#pragma unroll
            for (int j = 0; j < 4; ++j)
                bfr[j] = *(const short8*)&PT[(wn + j * 16 + r) * MP + k0];
#pragma unroll
            for (int i = 0; i < 4; ++i)
#pragma unroll
                for (int j = 0; j < 4; ++j)
                    acc[i][j] = __builtin_amdgcn_mfma_f32_16x16x32_bf16(af[i], bfr[j], acc[i][j], 0, 0, 0);
        }
#pragma unroll
        for (int j = 0; j < 4; ++j) {
            const int coll = wn + j * 16 + r;
#pragma unroll
            for (int i = 0; i < 4; ++i)
#pragma unroll
                for (int tt = 0; tt < 4; ++tt)
                    S2[(wm + i * 16 + qd * 4 + tt) * S2P + nb * 128 + coll] = f2bf(acc[i][j][tt]);
        }
        __syncthreads();
    }

    // Phase D: z2 = s2 @ W2a^T + b2a (K=256 via 2 halves), N=512 in 4 chunks
    ushortt* Wc = PT;
    ushortt* Cs = Ms;
    for (int nc = 0; nc < 4; ++nc) {
        f32x4 acc[4][4] = {};
#pragma unroll
        for (int kh = 0; kh < 2; ++kh) {
            __syncthreads();
#pragma unroll
            for (int k = 0; k < 8; ++k) {
                const int ch = t + k * 256;
                const int n = ch >> 4, kc = (ch & 15) * 8;
                *(us8*)&Wc[n * MP + kc] =
                    *(const us8*)&Wt2a[(size_t)(nc * 128 + n) * DD + kh * 128 + kc];
            }
            __syncthreads();
#pragma unroll
            for (int ks = 0; ks < 4; ++ks) {
                const int k0 = ks * 32 + qd * 8;
                short8 af[4], bfr[4];
#pragma unroll
                for (int i = 0; i < 4; ++i)
                    af[i] = *(const short8*)&S2[(wm + i * 16 + r) * S2P + kh * 128 + k0];
#pragma unroll
                for (int j = 0; j < 4; ++j)
                    bfr[j] = *(const short8*)&Wc[(wn + j * 16 + r) * MP + k0];
#pragma unroll
                for (int i = 0; i < 4; ++i)
#pragma unroll
                    for (int j = 0; j < 4; ++j)
                        acc[i][j] = __builtin_amdgcn_mfma_f32_16x16x32_bf16(af[i], bfr[j], acc[i][j], 0, 0, 0);
            }
        }
#pragma unroll
        for (int j = 0; j < 4; ++j) {
            const int coll = wn + j * 16 + r;
            const float bv = b2a[nc * 128 + coll];
            float s = 0.0f, q = 0.0f;
#pragma unroll
            for (int i = 0; i < 4; ++i)
#pragma unroll
                for (int tt = 0; tt < 4; ++tt) {
                    const float v = acc[i][j][tt] + bv;
                    Cs[(wm + i * 16 + qd * 4 + tt) * 128 + coll] = f2bf(v);
                    s += v;
                    q = fmaf(v, v, q);
                }
            s += __shfl_xor(s, 16); s += __shfl_xor(s, 32);
            q += __shfl_xor(q, 16); q += __shfl_xor(q, 32);
            if (qd == 0) {
                redS[(wave >> 1) * 128 + coll] = s;
                redQ[(wave >> 1) * 128 + coll] = q;
            }
        }
        __syncthreads();
        if (t < 128) {
            ps[(size_t)b * DD2 + nc * 128 + t] = redS[t] + redS[128 + t];
            pq[(size_t)b * DD2 + nc * 128 + t] = redQ[t] + redQ[128 + t];
        }
#pragma unroll
        for (int k = 0; k < 8; ++k) {
            const int ch = t + k * 256;
            const int row = ch >> 4, colc = (ch & 15) * 8;
            *(us8*)&z2[(size_t)(b * NPG + row) * DD2 + nc * 128 + colc] =
                *(const us8*)&Cs[row * 128 + colc];
        }
    }
}

// ---------------------------------------------------------------------------
// Mega tail: per-graph block (512 thr). node dots (scale/shift precomputed)
// -> edge scores -> stable descending rank-sort -> output writes.
__global__ __launch_bounds__(EPG) void sort_mega(const ushortt* __restrict__ h2,
                                                 const float* __restrict__ scale,
                                                 const float* __restrict__ shift,
                                                 const float* __restrict__ Wl,
                                                 const float* __restrict__ bl,
                                                 const int* __restrict__ ei,
                                                 float* __restrict__ out) {
    __shared__ float pa[NPG], pb[NPG];
    __shared__ float pw[EPG];
    __shared__ int ord[EPG];
    const int b = blockIdx.x, t = threadIdx.x;
    {
        const int wave = t >> 6, lane = t & 63;
        const float4 w0 = *(const float4*)&Wl[lane * 4];
        const float4 w1 = *(const float4*)&Wl[DD + lane * 4];
        const float4 sc4 = *(const float4*)&scale[lane * 4];
        const float4 sh4 = *(const float4*)&shift[lane * 4];
        for (int n = wave; n < NPG; n += 8) {
            const us4 z4 = *(const us4*)&h2[(size_t)(b * NPG + n) * DD + lane * 4];
            const float x0 = fmaf(bf2f(z4.x), sc4.x, sh4.x);
            const float x1 = fmaf(bf2f(z4.y), sc4.y, sh4.y);
            const float x2 = fmaf(bf2f(z4.z), sc4.z, sh4.z);
            const float x3 = fmaf(bf2f(z4.w), sc4.w, sh4.w);
            float sa = x0 * w0.x + x1 * w0.y + x2 * w0.z + x3 * w0.w;
            float sb = x0 * w1.x + x1 * w1.y + x2 * w1.z + x3 * w1.w;
#pragma unroll
            for (int off = 32; off >= 1; off >>= 1) {
                sa += __shfl_down(sa, off);
                sb += __shfl_down(sb, off);
            }
            if (lane == 0) { pa[n] = sa; pb[n] = sb; }
        }
    }
    __syncthreads();
    const int rl = ei[b * EPG + t] - b * NPG;
    const int cl = ei[ETOT + b * EPG + t] - b * NPG;
    const float v = pa[rl] + pb[cl] + bl[0];
    pw[t] = v;
    out[OFF_PRED + b * EPG + t] = v;
    __syncthreads();
    int rank = 0;
#pragma unroll 8
    for (int k = 0; k < EPG; ++k) {
        const float u = pw[k];
        rank += (u > v) || (u == v && k < t);
    }
    ord[rank] = t;
    __syncthreads();
    const int j = ord[t];
    const float wv = pw[j];
    const float e0 = (float)ei[b * EPG + j];
    const float e1 = (float)ei[ETOT + b * EPG + j];
    if (t < NRES) {
        out[OFF_CEI + b * NRES + t] = e0;
        out[OFF_CEI + BGR * NRES + b * NRES + t] = e1;
        out[OFF_CW + b * NRES + t] = wv;
    } else {
        const int p = t - NRES;
        out[OFF_FEI + b * NRES + p] = e0;
        out[OFF_FEI + BGR * NRES + b * NRES + p] = e1;
        out[OFF_FW + b * NRES + p] = -wv;
    }
}

// ---------------------------------------------------------------------------
extern "C" void kernel_launch(void* const* d_in, const int* in_sizes, int n_in,
                              void* d_out, int out_size, void* d_ws, size_t ws_size,
                              hipStream_t stream) {
    (void)in_sizes; (void)n_in; (void)out_size; (void)ws_size;
    const float* x    = (const float*)d_in[0];
    const int*   ei   = (const int*)d_in[1];
    const float* vemb = (const float*)d_in[3];
    const float* W1a  = (const float*)d_in[4];
    const float* b1a  = (const float*)d_in[5];
    const float* g1a  = (const float*)d_in[6];
    const float* be1a = (const float*)d_in[7];
    const float* W1b  = (const float*)d_in[8];
    const float* b1b  = (const float*)d_in[9];
    const float* g1   = (const float*)d_in[10];
    const float* be1  = (const float*)d_in[11];
    const float* W2a  = (const float*)d_in[12];
    const float* b2a  = (const float*)d_in[13];
    const float* g2a  = (const float*)d_in[14];
    const float* be2a = (const float*)d_in[15];
    const float* W2b  = (const float*)d_in[16];
    const float* b2b  = (const float*)d_in[17];
    const float* g2   = (const float*)d_in[18];
    const float* be2  = (const float*)d_in[19];
    const float* Wl   = (const float*)d_in[20];
    const float* bl   = (const float*)d_in[21];
    float* out = (float*)d_out;

    char* wp = (char*)d_ws;
    auto alloc = [&](size_t bytes) -> char* {
        char* r = wp;
        wp += (bytes + 255) & ~(size_t)255;
        return r;
    };
    ushortt* zb    = (ushortt*)alloc((size_t)NTOT * 512 * 2);  // z1 / z2
    ushortt* bufC  = (ushortt*)alloc((size_t)NTOT * 256 * 2);  // h1 / h2
    ushortt* Wt1a  = (ushortt*)alloc((size_t)DIN * DD2 * 2);
    ushortt* Wt1b  = (ushortt*)alloc((size_t)DD2 * DD * 2);
    ushortt* Wt2a  = (ushortt*)alloc((size_t)DD * DD2 * 2);
    ushortt* Wt2b  = (ushortt*)alloc((size_t)DD2 * DD * 2);
    float*   psA   = (float*)alloc((size_t)256 * DD2 * 4);     // z-stats
    float*   pqA   = (float*)alloc((size_t)256 * DD2 * 4);
    float*   psB   = (float*)alloc((size_t)256 * DD * 4);      // h-stats
    float*   pqB   = (float*)alloc((size_t)256 * DD * 4);
    float*   scA   = (float*)alloc(DD2 * 4);
    float*   shA   = (float*)alloc(DD2 * 4);
    float*   scB   = (float*)alloc(DD * 4);
    float*   shB   = (float*)alloc(DD * 4);

    // 1) weights
    prep_w<<<1792, 256, 0, stream>>>(W1a, W1b, W2a, W2b, Wt1a, Wt1b, Wt2a, Wt2b);

    // 2) adj + agg1 + z1 GEMM (+stats)
    layer1_front<<<BGR, 256, 0, stream>>>(x, ei, Wt1a, b1a, zb, psA, pqA);
    bn_finalize<<<2, 256, 0, stream>>>(psA, pqA, g1a, be1a, DD2, scA, shA);

    // 3) h1 = relu(BN(z1)) @ W1b + b1b  (+stats)
    gemm_bn<<<dim3(DD / BN, NTOT / BM), 256, 0, stream>>>(zb, Wt1b, scA, shA, b1b, bufC, psB, pqB);
    bn_finalize<<<1, 256, 0, stream>>>(psB, pqB, g1, be1, DD, scB, shB);

    // 4) post + adj + agg2 + z2 GEMM (+stats)
    layer2_mid<<<BGR, 256, 0, stream>>>(bufC, ei, scB, shB, vemb, Wt2a, b2a, zb, psA, pqA);
    bn_finalize<<<2, 256, 0, stream>>>(psA, pqA, g2a, be2a, DD2, scA, shA);

    // 5) h2 = relu(BN(z2)) @ W2b + b2b  (+stats)
    gemm_bn<<<dim3(DD / BN, NTOT / BM), 256, 0, stream>>>(zb, Wt2b, scA, shA, b2b, bufC, psB, pqB);
    bn_finalize<<<1, 256, 0, stream>>>(psB, pqB, g2, be2, DD, scB, shB);

    // 6) mega tail
    sort_mega<<<BGR, EPG, 0, stream>>>(bufC, scB, shB, Wl, bl, ei, out);
}

// Round 10
// 306.934 us; speedup vs baseline: 1.1606x; 1.0775x over previous
//
#include <hip/hip_runtime.h>

// Problem constants
#define BGR   256
#define NPG   128
#define EPG   512
#define DIN   128
#define DD    256
#define DD2   512
#define NTOT  (BGR * NPG)   // 32768
#define ETOT  (BGR * EPG)   // 131072
#define NRES  (EPG / 2)
#define NCHUNK 256
#define MP    136           // padded LDS stride (ushorts)

// Output layout (floats)
#define OFF_CEI  0
#define OFF_CW   (2 * BGR * NRES)
#define OFF_FEI  (OFF_CW + BGR * NRES)
#define OFF_FW   (OFF_FEI + 2 * BGR * NRES)
#define OFF_PRED (OFF_FW + BGR * NRES)

typedef unsigned short ushortt;
typedef __attribute__((ext_vector_type(4))) unsigned short us4;
typedef __attribute__((ext_vector_type(8))) unsigned short us8;
typedef __attribute__((ext_vector_type(8))) short short8;
typedef __attribute__((ext_vector_type(4))) float f32x4;

__device__ __forceinline__ ushortt f2bf(float f) {
    unsigned int u = __float_as_uint(f);
    unsigned int r = (u + 0x7fffu + ((u >> 16) & 1u)) >> 16;
    return (ushortt)r;
}
__device__ __forceinline__ float bf2f(ushortt u) {
    return __uint_as_float(((unsigned int)u) << 16);
}

__device__ __forceinline__ void g2lds16(const void* g, void* l) {
    __builtin_amdgcn_global_load_lds(
        (const __attribute__((address_space(1))) unsigned int*)g,
        (__attribute__((address_space(3))) unsigned int*)l, 16, 0, 0);
}

// ---------------------------------------------------------------------------
// prep: blocks 0..1791 transpose weights to bf16 [N][K]; blocks 1792..2047
// build per-graph adjacency (I + A^T), write Madj, and compute
// s1 = bf16(M @ bf16(x)) via MFMA entirely in LDS.
__global__ __launch_bounds__(256) void prep(const float* __restrict__ W1a,
                                            const float* __restrict__ W1b,
                                            const float* __restrict__ W2a,
                                            const float* __restrict__ W2b,
                                            const float* __restrict__ x,
                                            const int* __restrict__ ei,
                                            ushortt* __restrict__ Wt1a,
                                            ushortt* __restrict__ Wt1b,
                                            ushortt* __restrict__ Wt2a,
                                            ushortt* __restrict__ Wt2b,
                                            ushortt* __restrict__ Madj,
                                            ushortt* __restrict__ s1) {
    __shared__ __align__(16) char smem[102400];
    const int t = threadIdx.x;
    if (blockIdx.x < 1792) {
        const int idx = blockIdx.x * 256 + t;
        if (idx < 65536) {                       // W1a: 128x512
            const int k = idx >> 9, n = idx & 511;
            Wt1a[n * DIN + k] = f2bf(W1a[idx]);
        } else if (idx < 196608) {               // W1b: 512x256
            const int i = idx - 65536;
            const int k = i >> 8, n = i & 255;
            Wt1b[n * DD2 + k] = f2bf(W1b[i]);
        } else if (idx < 327680) {               // W2a: 256x512
            const int i = idx - 196608;
            const int k = i >> 9, n = i & 511;
            Wt2a[n * DD + k] = f2bf(W2a[i]);
        } else if (idx < 458752) {               // W2b: 512x256
            const int i = idx - 327680;
            const int k = i >> 8, n = i & 255;
            Wt2b[n * DD2 + k] = f2bf(W2b[i]);
        }
        return;
    }
    const int b = blockIdx.x - 1792;
    ushortt* Ms = (ushortt*)smem;                    // [128][136]
    int* cnt = (int*)(smem + 34816);                 // 64 KB
    ushortt* XT = (ushortt*)(smem + 34816);          // [128][136], after cnt dead
    ushortt* Cs = (ushortt*)(smem + 69632);          // [128][128], after cnt dead
    const int wave = t >> 6, lane = t & 63;
    const int qd = lane >> 4, r = lane & 15;
    const int wm = (wave >> 1) * 64, wn = (wave & 1) * 64;

    // adjacency counts (order-independent -> deterministic)
    for (int i = t; i < NPG * NPG; i += 256) cnt[i] = 0;
    __syncthreads();
    for (int e = t; e < EPG; e += 256) {
        const int src = ei[b * EPG + e] - b * NPG;
        const int dst = ei[ETOT + b * EPG + e] - b * NPG;
        atomicAdd(&cnt[dst * NPG + src], 1);
    }
    __syncthreads();
    // cnt -> Ms (bf16, padded) + global Madj
#pragma unroll
    for (int k = 0; k < 8; ++k) {
        const int ch = t + k * 256;
        const int m = ch >> 4, sc = (ch & 15) * 8;
        us8 o;
#pragma unroll
        for (int e = 0; e < 8; ++e)
            o[e] = f2bf((float)(cnt[m * NPG + sc + e] + (m == sc + e ? 1 : 0)));
        *(us8*)&Ms[m * MP + sc] = o;
        *(us8*)&Madj[(size_t)b * NPG * NPG + m * NPG + sc] = o;
    }
    __syncthreads();   // cnt dead

    // XT staging: chunked transpose, coalesced loads + one b128 write/chunk
#pragma unroll
    for (int k = 0; k < 8; ++k) {
        const int ch = t + k * 256;
        const int c = ch & 127, s8 = ch >> 7;
        us8 o;
#pragma unroll
        for (int j = 0; j < 8; ++j)
            o[j] = f2bf(x[(size_t)(b * NPG + s8 * 8 + j) * DIN + c]);
        *(us8*)&XT[c * MP + s8 * 8] = o;
    }
    __syncthreads();

    // s1 = Ms @ XT^T (128x128, K=128)
    f32x4 acc[4][4] = {};
#pragma unroll
    for (int ks = 0; ks < 4; ++ks) {
        const int k0 = ks * 32 + qd * 8;
        short8 af[4], bfr[4];
#pragma unroll
        for (int i = 0; i < 4; ++i)
            af[i] = *(const short8*)&Ms[(wm + i * 16 + r) * MP + k0];
#pragma unroll
        for (int j = 0; j < 4; ++j)
            bfr[j] = *(const short8*)&XT[(wn + j * 16 + r) * MP + k0];
#pragma unroll
        for (int i = 0; i < 4; ++i)
#pragma unroll
            for (int j = 0; j < 4; ++j)
                acc[i][j] = __builtin_amdgcn_mfma_f32_16x16x32_bf16(af[i], bfr[j], acc[i][j], 0, 0, 0);
    }
#pragma unroll
    for (int j = 0; j < 4; ++j) {
        const int coll = wn + j * 16 + r;
#pragma unroll
        for (int i = 0; i < 4; ++i)
#pragma unroll
            for (int tt = 0; tt < 4; ++tt)
                Cs[(wm + i * 16 + qd * 4 + tt) * 128 + coll] = f2bf(acc[i][j][tt]);
    }
    __syncthreads();
#pragma unroll
    for (int k = 0; k < 8; ++k) {
        const int ch = t + k * 256;
        const int row = ch >> 4, colc = (ch & 15) * 8;
        *(us8*)&s1[(size_t)(b * NPG + row) * DIN + colc] = *(const us8*)&Cs[row * 128 + colc];
    }
}

// ---------------------------------------------------------------------------
// z-GEMM: C = A@Wt^T + bias (bf16 out), fused fp32 BN partials, async staging.
#define BM 128
#define BN 128
#define BK 32
__global__ __launch_bounds__(256) void gemm_mfma(const ushortt* __restrict__ A,
                                                 const ushortt* __restrict__ Wt,
                                                 const float* __restrict__ bias,
                                                 ushortt* __restrict__ C,
                                                 float* __restrict__ psum,
                                                 float* __restrict__ psumsq,
                                                 int M, int N, int K) {
    __shared__ ushortt As[BM * BK];
    __shared__ ushortt Bs[BN * BK];
    __shared__ ushortt Cs[BM * BN];
    __shared__ float redS[2][BN];
    __shared__ float redQ[2][BN];
    const int tid  = threadIdx.x;
    const int wave = tid >> 6;
    const int lane = tid & 63;
    const int qd = lane >> 4;
    const int r  = lane & 15;
    const int wm = (wave >> 1) * 64;
    const int wn = (wave & 1) * 64;
    const int m0 = blockIdx.y * BM;
    const int n0 = blockIdx.x * BN;

    f32x4 acc[4][4] = {};

    for (int k0 = 0; k0 < K; k0 += BK) {
#pragma unroll
        for (int s = 0; s < 2; ++s) {
            const int o   = wave * 128 + s * 64 + lane;
            const int row = o >> 2;
            const int cg  = o & 3;
            g2lds16(A  + (size_t)(m0 + row) * K + k0 + cg * 8,
                    &As[(size_t)(wave * 128 + s * 64) * 8]);
            g2lds16(Wt + (size_t)(n0 + row) * K + k0 + cg * 8,
                    &Bs[(size_t)(wave * 128 + s * 64) * 8]);
        }
        __syncthreads();
        short8 af[4], bfr[4];
#pragma unroll
        for (int i = 0; i < 4; ++i)
            af[i] = *(const short8*)&As[(wm + i * 16 + r) * BK + qd * 8];
#pragma unroll
        for (int j = 0; j < 4; ++j)
            bfr[j] = *(const short8*)&Bs[(wn + j * 16 + r) * BK + qd * 8];
#pragma unroll
        for (int i = 0; i < 4; ++i)
#pragma unroll
            for (int j = 0; j < 4; ++j)
                acc[i][j] = __builtin_amdgcn_mfma_f32_16x16x32_bf16(af[i], bfr[j], acc[i][j], 0, 0, 0);
        __syncthreads();
    }

#pragma unroll
    for (int j = 0; j < 4; ++j) {
        const int coll = wn + j * 16 + r;
        const float bv = bias[n0 + coll];
        float s = 0.0f, q = 0.0f;
#pragma unroll
        for (int i = 0; i < 4; ++i)
#pragma unroll
            for (int t = 0; t < 4; ++t) {
                const float v = acc[i][j][t] + bv;
                Cs[(wm + i * 16 + qd * 4 + t) * BN + coll] = f2bf(v);
                s += v;
                q = fmaf(v, v, q);
            }
        s += __shfl_xor(s, 16); s += __shfl_xor(s, 32);
        q += __shfl_xor(q, 16); q += __shfl_xor(q, 32);
        if (qd == 0) {
            redS[wave >> 1][coll] = s;
            redQ[wave >> 1][coll] = q;
        }
    }
    __syncthreads();
    if (tid < BN) {
        psum[(size_t)blockIdx.y * N + n0 + tid]   = redS[0][tid] + redS[1][tid];
        psumsq[(size_t)blockIdx.y * N + n0 + tid] = redQ[0][tid] + redQ[1][tid];
    }
#pragma unroll
    for (int s8 = 0; s8 < 8; ++s8) {
        const int c    = tid + 256 * s8;
        const int row  = c >> 4;
        const int colc = (c & 15) * 8;
        const us8 v = *(const us8*)&Cs[row * BN + colc];
        *(us8*)&C[(size_t)(m0 + row) * N + n0 + colc] = v;
    }
}

// ---------------------------------------------------------------------------
__global__ __launch_bounds__(256) void bn_finalize(const float* __restrict__ psum,
                                                   const float* __restrict__ psumsq,
                                                   const float* __restrict__ g,
                                                   const float* __restrict__ be,
                                                   int ncols,
                                                   float* __restrict__ scale,
                                                   float* __restrict__ shift) {
    const int c = blockIdx.x * 256 + threadIdx.x;
    double s = 0.0, s2 = 0.0;
    for (int k = 0; k < NCHUNK; ++k) {
        s += (double)psum[(size_t)k * ncols + c];
        s2 += (double)psumsq[(size_t)k * ncols + c];
    }
    const double mean = s / (double)NTOT;
    const double var = s2 / (double)NTOT - mean * mean;
    const double rs = 1.0 / sqrt(var + 1e-5);
    const float sc = (float)((double)g[c] * rs);
    scale[c] = sc;
    shift[c] = (float)((double)be[c] - mean * (double)sc);
}

// ---------------------------------------------------------------------------
// h-GEMM: C = relu(BN(A))@Wt^T + bias, scale/shift precomputed, + fp32 stats.
__global__ __launch_bounds__(256) void gemm_bn(const ushortt* __restrict__ A,
                                               const ushortt* __restrict__ Wt,
                                               const float* __restrict__ scale,
                                               const float* __restrict__ shift,
                                               const float* __restrict__ bias,
                                               ushortt* __restrict__ C,
                                               float* __restrict__ psOut,
                                               float* __restrict__ pqOut) {
    __shared__ ushortt As[BM * BK];
    __shared__ ushortt Bs[BN * BK];
    __shared__ ushortt Cs[BM * BN];
    __shared__ float redS[2][BN];
    __shared__ float redQ[2][BN];
    __shared__ float scs[DD2], shs[DD2];
    const int tid  = threadIdx.x;
    const int wave = tid >> 6;
    const int lane = tid & 63;
    const int qd = lane >> 4;
    const int r  = lane & 15;
    const int wm = (wave >> 1) * 64;
    const int wn = (wave & 1) * 64;
    const int m0 = blockIdx.y * BM;
    const int n0 = blockIdx.x * BN;
    const int K = DD2, N = DD;

    for (int i = tid; i < K; i += 256) {
        scs[i] = scale[i];
        shs[i] = shift[i];
    }
    __syncthreads();

    f32x4 acc[4][4] = {};

    for (int k0 = 0; k0 < K; k0 += BK) {
#pragma unroll
        for (int s = 0; s < 2; ++s) {
            const int o   = wave * 128 + s * 64 + lane;
            const int row = o >> 2;
            const int cg  = o & 3;
            g2lds16(Wt + (size_t)(n0 + row) * K + k0 + cg * 8,
                    &Bs[(size_t)(wave * 128 + s * 64) * 8]);
        }
#pragma unroll
        for (int s = 0; s < 2; ++s) {
            const int o   = wave * 128 + s * 64 + lane;
            const int row = o >> 2;
            const int cg  = o & 3;
            const us8 a8 = *(const us8*)&A[(size_t)(m0 + row) * K + k0 + cg * 8];
            const float4 s4a = *(const float4*)&scs[k0 + cg * 8];
            const float4 s4b = *(const float4*)&scs[k0 + cg * 8 + 4];
            const float4 h4a = *(const float4*)&shs[k0 + cg * 8];
            const float4 h4b = *(const float4*)&shs[k0 + cg * 8 + 4];
            us8 t8;
            t8[0] = f2bf(fmaxf(fmaf(bf2f(a8[0]), s4a.x, h4a.x), 0.0f));
            t8[1] = f2bf(fmaxf(fmaf(bf2f(a8[1]), s4a.y, h4a.y), 0.0f));
            t8[2] = f2bf(fmaxf(fmaf(bf2f(a8[2]), s4a.z, h4a.z), 0.0f));
            t8[3] = f2bf(fmaxf(fmaf(bf2f(a8[3]), s4a.w, h4a.w), 0.0f));
            t8[4] = f2bf(fmaxf(fmaf(bf2f(a8[4]), s4b.x, h4b.x), 0.0f));
            t8[5] = f2bf(fmaxf(fmaf(bf2f(a8[5]), s4b.y, h4b.y), 0.0f));
            t8[6] = f2bf(fmaxf(fmaf(bf2f(a8[6]), s4b.z, h4b.z), 0.0f));
            t8[7] = f2bf(fmaxf(fmaf(bf2f(a8[7]), s4b.w, h4b.w), 0.0f));
            *(us8*)&As[row * BK + cg * 8] = t8;
        }
        __syncthreads();
        short8 af[4], bfr[4];
#pragma unroll
        for (int i = 0; i < 4; ++i)
            af[i] = *(const short8*)&As[(wm + i * 16 + r) * BK + qd * 8];
#pragma unroll
        for (int j = 0; j < 4; ++j)
            bfr[j] = *(const short8*)&Bs[(wn + j * 16 + r) * BK + qd * 8];
#pragma unroll
        for (int i = 0; i < 4; ++i)
#pragma unroll
            for (int j = 0; j < 4; ++j)
                acc[i][j] = __builtin_amdgcn_mfma_f32_16x16x32_bf16(af[i], bfr[j], acc[i][j], 0, 0, 0);
        __syncthreads();
    }

#pragma unroll
    for (int j = 0; j < 4; ++j) {
        const int coll = wn + j * 16 + r;
        const float bv = bias[n0 + coll];
        float s = 0.0f, q = 0.0f;
#pragma unroll
        for (int i = 0; i < 4; ++i)
#pragma unroll
            for (int t = 0; t < 4; ++t) {
                const float v = acc[i][j][t] + bv;
                Cs[(wm + i * 16 + qd * 4 + t) * BN + coll] = f2bf(v);
                s += v;
                q = fmaf(v, v, q);
            }
        s += __shfl_xor(s, 16); s += __shfl_xor(s, 32);
        q += __shfl_xor(q, 16); q += __shfl_xor(q, 32);
        if (qd == 0) {
            redS[wave >> 1][coll] = s;
            redQ[wave >> 1][coll] = q;
        }
    }
    __syncthreads();
    if (tid < BN) {
        psOut[(size_t)blockIdx.y * N + n0 + tid] = redS[0][tid] + redS[1][tid];
        pqOut[(size_t)blockIdx.y * N + n0 + tid] = redQ[0][tid] + redQ[1][tid];
    }
#pragma unroll
    for (int s8 = 0; s8 < 8; ++s8) {
        const int c    = tid + 256 * s8;
        const int row  = c >> 4;
        const int colc = (c & 15) * 8;
        const us8 v = *(const us8*)&Cs[row * BN + colc];
        *(us8*)&C[(size_t)(m0 + row) * N + n0 + colc] = v;
    }
}

// ---------------------------------------------------------------------------
// agg2: fused finalize(g1) for this block's 128 cols + post staging
// (chunked, conflict-light) + s2 = M @ post via MFMA. Grid (2, BGR).
__global__ __launch_bounds__(256) void agg2_mm(const ushortt* __restrict__ h,
                                               const float* __restrict__ psum,
                                               const float* __restrict__ psumsq,
                                               const float* __restrict__ g,
                                               const float* __restrict__ be,
                                               const float* __restrict__ vemb,
                                               const ushortt* __restrict__ Madj,
                                               ushortt* __restrict__ s2) {
    __shared__ ushortt Ms[NPG * MP];
    __shared__ ushortt PT[NPG * MP];
    __shared__ double redS[2][128];
    __shared__ double redQ[2][128];
    __shared__ float scs[128], shs[128];
    const int nb = blockIdx.x, b = blockIdx.y, t = threadIdx.x;
    const int wave = t >> 6, lane = t & 63;
    const int qd = lane >> 4, r = lane & 15;
    const int wm = (wave >> 1) * 64, wn = (wave & 1) * 64;
    const ushortt* Mg = Madj + (size_t)b * NPG * NPG;
#pragma unroll
    for (int k = 0; k < 8; ++k) {
        const int ch = t + k * 256;
        const int m = ch >> 4, sc = (ch & 15) * 8;
        *(us8*)&Ms[m * MP + sc] = *(const us8*)&Mg[m * NPG + sc];
    }
    // fused finalize for this block's 128 columns
    {
        const int cl = t & 127, half = t >> 7;
        const int c = nb * 128 + cl;
        double s = 0.0, q = 0.0;
#pragma unroll 4
        for (int k = half * 128; k < half * 128 + 128; ++k) {
            s += (double)psum[(size_t)k * DD + c];
            q += (double)psumsq[(size_t)k * DD + c];
        }
        redS[half][cl] = s;
        redQ[half][cl] = q;
    }
    __syncthreads();
    if (t < 128) {
        const int c = nb * 128 + t;
        const double s = redS[0][t] + redS[1][t];
        const double q = redQ[0][t] + redQ[1][t];
        const double mean = s / (double)NTOT;
        const double var = q / (double)NTOT - mean * mean;
        const double rs = 1.0 / sqrt(var + 1e-5);
        const float sc = (float)((double)g[c] * rs);
        scs[t] = sc;
        shs[t] = (float)((double)be[c] - mean * (double)sc);
    }
    __syncthreads();
    // post staging: chunked transpose (coalesced loads, b128 writes)
#pragma unroll
    for (int k = 0; k < 8; ++k) {
        const int ch = t + k * 256;
        const int cl = ch & 127, s8 = ch >> 7;
        const float scv = scs[cl], shv = shs[cl], vev = vemb[nb * 128 + cl];
        us8 o;
#pragma unroll
        for (int j = 0; j < 8; ++j) {
            float v = fmaf(bf2f(h[(size_t)(b * NPG + s8 * 8 + j) * DD + nb * 128 + cl]), scv, shv);
            o[j] = f2bf(fmaxf(v, 0.0f) + vev);
        }
        *(us8*)&PT[cl * MP + s8 * 8] = o;
    }
    __syncthreads();
    f32x4 acc[4][4] = {};
#pragma unroll
    for (int ks = 0; ks < 4; ++ks) {
        const int k0 = ks * 32 + qd * 8;
        short8 af[4], bfr[4];
#pragma unroll
        for (int i = 0; i < 4; ++i)
            af[i] = *(const short8*)&Ms[(wm + i * 16 + r) * MP + k0];
#pragma unroll
        for (int j = 0; j < 4; ++j)
            bfr[j] = *(const short8*)&PT[(wn + j * 16 + r) * MP + k0];
#pragma unroll
        for (int i = 0; i < 4; ++i)
#pragma unroll
            for (int j = 0; j < 4; ++j)
                acc[i][j] = __builtin_amdgcn_mfma_f32_16x16x32_bf16(af[i], bfr[j], acc[i][j], 0, 0, 0);
    }
    __syncthreads();
    ushortt* Cs = Ms;   // reuse, stride 128
#pragma unroll
    for (int j = 0; j < 4; ++j) {
        const int coll = wn + j * 16 + r;
#pragma unroll
        for (int i = 0; i < 4; ++i)
#pragma unroll
            for (int tt = 0; tt < 4; ++tt)
                Cs[(wm + i * 16 + qd * 4 + tt) * 128 + coll] = f2bf(acc[i][j][tt]);
    }
    __syncthreads();
#pragma unroll
    for (int k = 0; k < 8; ++k) {
        const int ch = t + k * 256;
        const int row = ch >> 4, colc = (ch & 15) * 8;
        *(us8*)&s2[(size_t)(b * NPG + row) * DD + nb * 128 + colc] =
            *(const us8*)&Cs[row * 128 + colc];
    }
}

// ---------------------------------------------------------------------------
// Mega tail: per-graph block (512 thr). Fused finalize(g2,be2) -> node dots
// -> edge scores -> stable descending rank-sort -> output writes.
__global__ __launch_bounds__(EPG) void sort_mega(const ushortt* __restrict__ h2,
                                                 const float* __restrict__ psum,
                                                 const float* __restrict__ psumsq,
                                                 const float* __restrict__ g,
                                                 const float* __restrict__ be,
                                                 const float* __restrict__ Wl,
                                                 const float* __restrict__ bl,
                                                 const int* __restrict__ ei,
                                                 float* __restrict__ out) {
    __shared__ double redS[2][DD];
    __shared__ double redQ[2][DD];
    __shared__ float scs[DD], shs[DD];
    __shared__ float pa[NPG], pb[NPG];
    __shared__ float pw[EPG];
    __shared__ int ord[EPG];
    const int b = blockIdx.x, t = threadIdx.x;
    {
        const int c = t & 255, half = t >> 8;
        double s = 0.0, q = 0.0;
#pragma unroll 4
        for (int k = half * 128; k < half * 128 + 128; ++k) {
            s += (double)psum[(size_t)k * DD + c];
            q += (double)psumsq[(size_t)k * DD + c];
        }
        redS[half][c] = s;
        redQ[half][c] = q;
    }
    __syncthreads();
    if (t < DD) {
        const double s = redS[0][t] + redS[1][t];
        const double q = redQ[0][t] + redQ[1][t];
        const double mean = s / (double)NTOT;
        const double var = q / (double)NTOT - mean * mean;
        const double rs = 1.0 / sqrt(var + 1e-5);
        const float sc = (float)((double)g[t] * rs);
        scs[t] = sc;
        shs[t] = (float)((double)be[t] - mean * (double)sc);
    }
    __syncthreads();
    {
        const int wave = t >> 6, lane = t & 63;
        const float4 w0 = *(const float4*)&Wl[lane * 4];
        const float4 w1 = *(const float4*)&Wl[DD + lane * 4];
        const float4 sc4 = *(const float4*)&scs[lane * 4];
        const float4 sh4 = *(const float4*)&shs[lane * 4];
        for (int n = wave; n < NPG; n += 8) {
            const us4 z4 = *(const us4*)&h2[(size_t)(b * NPG + n) * DD + lane * 4];
            const float x0 = fmaf(bf2f(z4.x), sc4.x, sh4.x);
            const float x1 = fmaf(bf2f(z4.y), sc4.y, sh4.y);
            const float x2 = fmaf(bf2f(z4.z), sc4.z, sh4.z);
            const float x3 = fmaf(bf2f(z4.w), sc4.w, sh4.w);
            float sa = x0 * w0.x + x1 * w0.y + x2 * w0.z + x3 * w0.w;
            float sb = x0 * w1.x + x1 * w1.y + x2 * w1.z + x3 * w1.w;
#pragma unroll
            for (int off = 32; off >= 1; off >>= 1) {
                sa += __shfl_down(sa, off);
                sb += __shfl_down(sb, off);
            }
            if (lane == 0) { pa[n] = sa; pb[n] = sb; }
        }
    }
    __syncthreads();
    const int rl = ei[b * EPG + t] - b * NPG;
    const int cl = ei[ETOT + b * EPG + t] - b * NPG;
    const float v = pa[rl] + pb[cl] + bl[0];
    pw[t] = v;
    out[OFF_PRED + b * EPG + t] = v;
    __syncthreads();
    int rank = 0;
#pragma unroll 8
    for (int k = 0; k < EPG; ++k) {
        const float u = pw[k];
        rank += (u > v) || (u == v && k < t);
    }
    ord[rank] = t;
    __syncthreads();
    const int j = ord[t];
    const float wv = pw[j];
    const float e0 = (float)ei[b * EPG + j];
    const float e1 = (float)ei[ETOT + b * EPG + j];
    if (t < NRES) {
        out[OFF_CEI + b * NRES + t] = e0;
        out[OFF_CEI + BGR * NRES + b * NRES + t] = e1;
        out[OFF_CW + b * NRES + t] = wv;
    } else {
        const int p = t - NRES;
        out[OFF_FEI + b * NRES + p] = e0;
        out[OFF_FEI + BGR * NRES + b * NRES + p] = e1;
        out[OFF_FW + b * NRES + p] = -wv;
    }
}

// ---------------------------------------------------------------------------
extern "C" void kernel_launch(void* const* d_in, const int* in_sizes, int n_in,
                              void* d_out, int out_size, void* d_ws, size_t ws_size,
                              hipStream_t stream) {
    (void)in_sizes; (void)n_in; (void)out_size; (void)ws_size;
    const float* x    = (const float*)d_in[0];
    const int*   ei   = (const int*)d_in[1];
    const float* vemb = (const float*)d_in[3];
    const float* W1a  = (const float*)d_in[4];
    const float* b1a  = (const float*)d_in[5];
    const float* g1a  = (const float*)d_in[6];
    const float* be1a = (const float*)d_in[7];
    const float* W1b  = (const float*)d_in[8];
    const float* b1b  = (const float*)d_in[9];
    const float* g1   = (const float*)d_in[10];
    const float* be1  = (const float*)d_in[11];
    const float* W2a  = (const float*)d_in[12];
    const float* b2a  = (const float*)d_in[13];
    const float* g2a  = (const float*)d_in[14];
    const float* be2a = (const float*)d_in[15];
    const float* W2b  = (const float*)d_in[16];
    const float* b2b  = (const float*)d_in[17];
    const float* g2   = (const float*)d_in[18];
    const float* be2  = (const float*)d_in[19];
    const float* Wl   = (const float*)d_in[20];
    const float* bl   = (const float*)d_in[21];
    float* out = (float*)d_out;

    char* wp = (char*)d_ws;
    auto alloc = [&](size_t bytes) -> char* {
        char* r = wp;
        wp += (bytes + 255) & ~(size_t)255;
        return r;
    };
    ushortt* zb    = (ushortt*)alloc((size_t)NTOT * 512 * 2);  // z1 / z2
    ushortt* bufC  = (ushortt*)alloc((size_t)NTOT * 256 * 2);  // h1 / h2
    ushortt* bufS1 = (ushortt*)alloc((size_t)NTOT * 128 * 2);  // s1
    ushortt* bufS2 = (ushortt*)alloc((size_t)NTOT * 256 * 2);  // s2
    ushortt* Madj  = (ushortt*)alloc((size_t)BGR * NPG * NPG * 2);
    ushortt* Wt1a  = (ushortt*)alloc((size_t)DIN * DD2 * 2);
    ushortt* Wt1b  = (ushortt*)alloc((size_t)DD2 * DD * 2);
    ushortt* Wt2a  = (ushortt*)alloc((size_t)DD * DD2 * 2);
    ushortt* Wt2b  = (ushortt*)alloc((size_t)DD2 * DD * 2);
    float*   psA   = (float*)alloc((size_t)256 * DD2 * 4);
    float*   pqA   = (float*)alloc((size_t)256 * DD2 * 4);
    float*   psB   = (float*)alloc((size_t)256 * DD * 4);
    float*   pqB   = (float*)alloc((size_t)256 * DD * 4);
    float*   scA   = (float*)alloc(DD2 * 4);
    float*   shA   = (float*)alloc(DD2 * 4);

    // 1) weights + (adjacency -> Madj, s1) in one dispatch
    prep<<<2048, 256, 0, stream>>>(W1a, W1b, W2a, W2b, x, ei,
                                   Wt1a, Wt1b, Wt2a, Wt2b, Madj, bufS1);

    // 2) z1 = s1 @ W1a + b1a (+stats)
    gemm_mfma<<<dim3(DD2 / BN, NTOT / BM), 256, 0, stream>>>(bufS1, Wt1a, b1a, zb, psA, pqA, NTOT, DD2, DIN);
    bn_finalize<<<2, 256, 0, stream>>>(psA, pqA, g1a, be1a, DD2, scA, shA);

    // 3) h1 = relu(BN(z1)) @ W1b + b1b (+stats)
    gemm_bn<<<dim3(DD / BN, NTOT / BM), 256, 0, stream>>>(zb, Wt1b, scA, shA, b1b, bufC, psB, pqB);

    // 4) s2 = M @ (relu(BN(h1)) + vemb)  [finalize(g1) fused]
    agg2_mm<<<dim3(2, BGR), 256, 0, stream>>>(bufC, psB, pqB, g1, be1, vemb, Madj, bufS2);

    // 5) z2 = s2 @ W2a + b2a (+stats)
    gemm_mfma<<<dim3(DD2 / BN, NTOT / BM), 256, 0, stream>>>(bufS2, Wt2a, b2a, zb, psA, pqA, NTOT, DD2, DD);
    bn_finalize<<<2, 256, 0, stream>>>(psA, pqA, g2a, be2a, DD2, scA, shA);

    // 6) h2 = relu(BN(z2)) @ W2b + b2b (+stats)
    gemm_bn<<<dim3(DD / BN, NTOT / BM), 256, 0, stream>>>(zb, Wt2b, scA, shA, b2b, bufC, psB, pqB);

    // 7) mega tail (finalize(g2) fused)
    sort_mega<<<BGR, EPG, 0, stream>>>(bufC, psB, pqB, g2, be2, Wl, bl, ei, out);
}